// Round 1
// baseline (743.535 us; speedup 1.0000x reference)
//
#include <hip/hip_runtime.h>
#include <math.h>

#define BATCH 4096
#define DIN   2048
#define DOUT  2048
#define DEPTH 16

// probs[j] = (prod_{d,g} cos(W[d, j, g]))^2 / DIN
// Derivation: reference's scan state starts uniform and the rotation step
// maps uniform -> uniform (sin terms cancel), leaving s = s0 * prod(cos).
__global__ __launch_bounds__(256) void probs_kernel(const float* __restrict__ W,
                                                    float* __restrict__ probs) {
    int j = blockIdx.x * 256 + threadIdx.x;
    if (j >= DOUT) return;
    const float* base = W + (size_t)j * DOUT;
    float prod = 1.0f;
#pragma unroll
    for (int d = 0; d < DEPTH; ++d) {
        const float* p = base + (size_t)d * DIN * DOUT;
        prod *= cosf(p[0]);
        prod *= cosf(p[1]);
        prod *= cosf(p[2]);
    }
    probs[j] = prod * prod * (1.0f / (float)DIN);
}

// C[b, o] = tanh(x @ Wc + bias + probs)  — 128x128 tile, BK=16, 8x8 per thread.
__global__ __launch_bounds__(256) void gemm_tanh_kernel(
    const float* __restrict__ A,    // [BATCH, DIN]
    const float* __restrict__ Bw,   // [DIN, DOUT]
    const float* __restrict__ bias, // [DOUT]
    const float* __restrict__ probs,// [DOUT]
    float* __restrict__ C)          // [BATCH, DOUT]
{
    __shared__ float As[16][128 + 4];  // A tile transposed: As[k][m]
    __shared__ float Bs[16][128 + 4];  // Bs[k][n]; row stride 132*4=528B (16B aligned)

    const int tid = threadIdx.x;
    const int block_row = blockIdx.y * 128;
    const int block_col = blockIdx.x * 128;

    const int tr = (tid >> 4) << 3;  // 0..120 step 8
    const int tc = (tid & 15) << 3;  // 0..120 step 8

    // A staging: 128x16 floats = 512 float4; 2 per thread
    const int a_row = tid >> 2;        // 0..63
    const int a_col = (tid & 3) << 2;  // 0,4,8,12
    // B staging: 16x128 floats = 512 float4; 2 per thread
    const int b_row = tid >> 5;        // 0..7
    const int b_col = (tid & 31) << 2; // 0..124

    const float* Aptr0 = A + (size_t)(block_row + a_row) * DIN + a_col;
    const float* Aptr1 = Aptr0 + (size_t)64 * DIN;
    const float* Bptr0 = Bw + (size_t)b_row * DOUT + block_col + b_col;
    const float* Bptr1 = Bptr0 + (size_t)8 * DOUT;

    float acc[8][8] = {};

    for (int k0 = 0; k0 < DIN; k0 += 16) {
        float4 a0 = *(const float4*)(Aptr0 + k0);
        float4 a1 = *(const float4*)(Aptr1 + k0);
        float4 b0 = *(const float4*)(Bptr0 + (size_t)k0 * DOUT);
        float4 b1 = *(const float4*)(Bptr1 + (size_t)k0 * DOUT);

        __syncthreads();  // previous compute done before overwrite

        As[a_col + 0][a_row] = a0.x;
        As[a_col + 1][a_row] = a0.y;
        As[a_col + 2][a_row] = a0.z;
        As[a_col + 3][a_row] = a0.w;
        As[a_col + 0][a_row + 64] = a1.x;
        As[a_col + 1][a_row + 64] = a1.y;
        As[a_col + 2][a_row + 64] = a1.z;
        As[a_col + 3][a_row + 64] = a1.w;
        *(float4*)&Bs[b_row][b_col]     = b0;
        *(float4*)&Bs[b_row + 8][b_col] = b1;

        __syncthreads();

#pragma unroll
        for (int kk = 0; kk < 16; ++kk) {
            float ar[8], br[8];
#pragma unroll
            for (int i = 0; i < 8; ++i) ar[i] = As[kk][tr + i];
#pragma unroll
            for (int i = 0; i < 8; ++i) br[i] = Bs[kk][tc + i];
#pragma unroll
            for (int i = 0; i < 8; ++i)
#pragma unroll
                for (int jj = 0; jj < 8; ++jj)
                    acc[i][jj] = fmaf(ar[i], br[jj], acc[i][jj]);
        }
    }

    // epilogue: + bias + probs, tanh
    float bp[8];
#pragma unroll
    for (int jj = 0; jj < 8; ++jj)
        bp[jj] = bias[block_col + tc + jj] + probs[block_col + tc + jj];

#pragma unroll
    for (int i = 0; i < 8; ++i) {
        float* crow = C + (size_t)(block_row + tr + i) * DOUT + block_col + tc;
        float4 o0, o1;
        o0.x = tanhf(acc[i][0] + bp[0]);
        o0.y = tanhf(acc[i][1] + bp[1]);
        o0.z = tanhf(acc[i][2] + bp[2]);
        o0.w = tanhf(acc[i][3] + bp[3]);
        o1.x = tanhf(acc[i][4] + bp[4]);
        o1.y = tanhf(acc[i][5] + bp[5]);
        o1.z = tanhf(acc[i][6] + bp[6]);
        o1.w = tanhf(acc[i][7] + bp[7]);
        *(float4*)(crow)     = o0;
        *(float4*)(crow + 4) = o1;
    }
}

extern "C" void kernel_launch(void* const* d_in, const int* in_sizes, int n_in,
                              void* d_out, int out_size, void* d_ws, size_t ws_size,
                              hipStream_t stream) {
    const float* x  = (const float*)d_in[0];  // [4096, 2048]
    const float* W  = (const float*)d_in[1];  // [16, 2048, 2048]
    const float* cw = (const float*)d_in[2];  // [2048, 2048]
    const float* cb = (const float*)d_in[3];  // [2048]
    float* out   = (float*)d_out;
    float* probs = (float*)d_ws;              // 2048 floats of scratch

    probs_kernel<<<DOUT / 256, 256, 0, stream>>>(W, probs);

    dim3 grid(DOUT / 128, BATCH / 128);
    gemm_tanh_kernel<<<grid, dim3(256), 0, stream>>>(x, cw, cb, probs, out);
}

// Round 2
// 432.553 us; speedup vs baseline: 1.7189x; 1.7189x over previous
//
#include <hip/hip_runtime.h>
#include <math.h>

#define BATCH 4096
#define DIN   2048
#define DOUT  2048
#define DEPTH 16

typedef unsigned short u16;
typedef __attribute__((ext_vector_type(8))) short short8;  // 8 bf16 = 4 VGPRs (guide §3)
typedef __attribute__((ext_vector_type(4))) float f32x4;

// ---------- helpers ----------

__device__ static inline unsigned bf16_rn(float x) {
    unsigned u = __float_as_uint(x);
    return (u + 0x7FFFu + ((u >> 16) & 1u)) >> 16;  // RN-even to bf16 bits
}

__device__ static inline float tanh_fast(float z) {
    float zc = fminf(fmaxf(z, -15.0f), 15.0f);
    float e = __builtin_amdgcn_exp2f(zc * 2.8853900817779268f);  // exp(2z)
    return (e - 1.0f) * __builtin_amdgcn_rcpf(e + 1.0f);
}

__device__ static inline void async16(u16* lds, const u16* g) {
    __builtin_amdgcn_global_load_lds(
        (const __attribute__((address_space(1))) void*)g,
        (__attribute__((address_space(3))) void*)lds, 16, 0, 0);
}

// ---------- probs: probs[j] = (prod cos(W[d,j,g]))^2 / DIN ----------
// d-parallel: 16 lanes per j, shfl product-reduce. 128 blocks x 256 thr.
__global__ __launch_bounds__(256) void probs_kernel(const float* __restrict__ W,
                                                    float* __restrict__ probs) {
    int tid = threadIdx.x;
    int jl = tid >> 4, d = tid & 15;
    int j = blockIdx.x * 16 + jl;
    const float* p = W + (size_t)d * DIN * DOUT + (size_t)j * DOUT;
    float pr = cosf(p[0]) * cosf(p[1]) * cosf(p[2]);
#pragma unroll
    for (int off = 1; off < 16; off <<= 1) pr *= __shfl_xor(pr, off, 16);
    if (d == 0) probs[j] = pr * pr * (1.0f / (float)DIN);
}

// ---------- x -> hi/lo bf16 (RN split) ----------
__global__ __launch_bounds__(256) void convert_x_kernel(const float* __restrict__ x,
                                                        u16* __restrict__ xh,
                                                        u16* __restrict__ xl) {
    int i = (blockIdx.x * 256 + threadIdx.x) * 4;
    float4 v = *(const float4*)(x + i);
    ushort4 h, l;
    float vv[4] = {v.x, v.y, v.z, v.w};
    u16 hh[4], ll[4];
#pragma unroll
    for (int c = 0; c < 4; ++c) {
        unsigned hb = bf16_rn(vv[c]);
        hh[c] = (u16)hb;
        float r = vv[c] - __uint_as_float(hb << 16);
        ll[c] = (u16)bf16_rn(r);
    }
    h.x = hh[0]; h.y = hh[1]; h.z = hh[2]; h.w = hh[3];
    l.x = ll[0]; l.y = ll[1]; l.z = ll[2]; l.w = ll[3];
    *(ushort4*)(xh + i) = h;
    *(ushort4*)(xl + i) = l;
}

// ---------- W[k][n] -> Wt_hi/Wt_lo[n][k] (transpose + RN split) ----------
__global__ __launch_bounds__(256) void transpose_w_kernel(const float* __restrict__ W,
                                                          u16* __restrict__ wh,
                                                          u16* __restrict__ wl) {
    __shared__ float t[32][33];
    int n0 = blockIdx.x * 32, k0 = blockIdx.y * 32;
    int tx = threadIdx.x & 31, ty = threadIdx.x >> 5;  // ty 0..7
#pragma unroll
    for (int i = 0; i < 4; ++i)
        t[ty + i * 8][tx] = W[(size_t)(k0 + ty + i * 8) * DOUT + n0 + tx];
    __syncthreads();
#pragma unroll
    for (int i = 0; i < 4; ++i) {
        float v = t[tx][ty + i * 8];
        size_t o = (size_t)(n0 + ty + i * 8) * DIN + k0 + tx;
        unsigned hb = bf16_rn(v);
        wh[o] = (u16)hb;
        float r = v - __uint_as_float(hb << 16);
        wl[o] = (u16)bf16_rn(r);
    }
}

// ---------- MFMA GEMM: C = tanh(x@W + bias + probs), bf16x3 ----------
// 128x128 tile, 4 waves (2x2), each wave 4x4 tiles of 16x16x32, BK=32.
// LDS rows of 32 bf16 (64B), XOR swizzle phys_quad = quad ^ ((row>>1)&3).
__global__ __launch_bounds__(256, 2) void gemm_mfma_kernel(
    const u16* __restrict__ xh, const u16* __restrict__ xl,
    const u16* __restrict__ wh, const u16* __restrict__ wl,
    const float* __restrict__ bias, const float* __restrict__ probs,
    float* __restrict__ C)
{
    __shared__ u16 sAh[4096];
    __shared__ u16 sAl[4096];
    __shared__ u16 sBh[4096];
    __shared__ u16 sBl[4096];

    const int tid = threadIdx.x;
    const int lane = tid & 63;
    const int wave = tid >> 6;
    const int bR = blockIdx.y * 128;
    const int bC = blockIdx.x * 128;

    // Each wave DMAs one array (A_hi/A_lo/B_hi/B_lo), 8 chunks of 1KB.
    const u16* gsrc = (wave == 0) ? xh + (size_t)bR * DIN
                    : (wave == 1) ? xl + (size_t)bR * DIN
                    : (wave == 2) ? wh + (size_t)bC * DIN
                                  : wl + (size_t)bC * DIN;
    u16* lbase = (wave == 0) ? sAh : (wave == 1) ? sAl : (wave == 2) ? sBh : sBl;

    int goff[8];
#pragma unroll
    for (int i = 0; i < 8; ++i) {
        int row = i * 16 + (lane >> 2);
        int lq = (lane & 3) ^ ((row >> 1) & 3);  // logical quad feeding phys pos lane&3
        goff[i] = row * DIN + lq * 8;
    }

    const int wm = wave >> 1, wn = wave & 1;
    const int colL = lane & 15, quad = lane >> 4;

    int aoff[4], boff[4];
#pragma unroll
    for (int mt = 0; mt < 4; ++mt) {
        int r = wm * 64 + mt * 16 + colL;
        aoff[mt] = r * 32 + (quad ^ ((r >> 1) & 3)) * 8;
    }
#pragma unroll
    for (int nt = 0; nt < 4; ++nt) {
        int r = wn * 64 + nt * 16 + colL;
        boff[nt] = r * 32 + (quad ^ ((r >> 1) & 3)) * 8;
    }

    f32x4 acc[4][4];
#pragma unroll
    for (int mt = 0; mt < 4; ++mt)
#pragma unroll
        for (int nt = 0; nt < 4; ++nt) acc[mt][nt] = (f32x4){0.f, 0.f, 0.f, 0.f};

    for (int k0 = 0; k0 < DIN; k0 += 32) {
        __syncthreads();  // prior iteration's frag reads done before overwrite
#pragma unroll
        for (int i = 0; i < 8; ++i)
            async16(lbase + i * 512, gsrc + goff[i] + k0);
        __syncthreads();  // drains vmcnt before barrier (m97 structure)

        short8 ah[4], al[4], bh[4], bl[4];
#pragma unroll
        for (int mt = 0; mt < 4; ++mt) {
            ah[mt] = *(const short8*)&sAh[aoff[mt]];
            al[mt] = *(const short8*)&sAl[aoff[mt]];
        }
#pragma unroll
        for (int nt = 0; nt < 4; ++nt) {
            bh[nt] = *(const short8*)&sBh[boff[nt]];
            bl[nt] = *(const short8*)&sBl[boff[nt]];
        }

#pragma unroll
        for (int mt = 0; mt < 4; ++mt)
#pragma unroll
            for (int nt = 0; nt < 4; ++nt) {
                acc[mt][nt] = __builtin_amdgcn_mfma_f32_16x16x32_bf16(
                    ah[mt], bh[nt], acc[mt][nt], 0, 0, 0);
                acc[mt][nt] = __builtin_amdgcn_mfma_f32_16x16x32_bf16(
                    ah[mt], bl[nt], acc[mt][nt], 0, 0, 0);
                acc[mt][nt] = __builtin_amdgcn_mfma_f32_16x16x32_bf16(
                    al[mt], bh[nt], acc[mt][nt], 0, 0, 0);
            }
    }

    // epilogue: C/D map col=lane&15, row=quad*4+reg (verified m89/m91)
    float bp[4];
#pragma unroll
    for (int nt = 0; nt < 4; ++nt) {
        int c = bC + wn * 64 + nt * 16 + colL;
        bp[nt] = bias[c] + probs[c];
    }
#pragma unroll
    for (int mt = 0; mt < 4; ++mt)
#pragma unroll
        for (int nt = 0; nt < 4; ++nt) {
            int c = bC + wn * 64 + nt * 16 + colL;
#pragma unroll
            for (int reg = 0; reg < 4; ++reg) {
                int r = bR + wm * 64 + mt * 16 + quad * 4 + reg;
                C[(size_t)r * DOUT + c] = tanh_fast(acc[mt][nt][reg] + bp[nt]);
            }
        }
}

// ---------- fallback f32 GEMM (round-1, used if ws too small) ----------
__global__ __launch_bounds__(256) void gemm_tanh_kernel(
    const float* __restrict__ A, const float* __restrict__ Bw,
    const float* __restrict__ bias, const float* __restrict__ probs,
    float* __restrict__ C)
{
    __shared__ float As[16][128 + 4];
    __shared__ float Bs[16][128 + 4];
    const int tid = threadIdx.x;
    const int block_row = blockIdx.y * 128;
    const int block_col = blockIdx.x * 128;
    const int tr = (tid >> 4) << 3;
    const int tc = (tid & 15) << 3;
    const int a_row = tid >> 2;
    const int a_col = (tid & 3) << 2;
    const int b_row = tid >> 5;
    const int b_col = (tid & 31) << 2;
    const float* Aptr0 = A + (size_t)(block_row + a_row) * DIN + a_col;
    const float* Aptr1 = Aptr0 + (size_t)64 * DIN;
    const float* Bptr0 = Bw + (size_t)b_row * DOUT + block_col + b_col;
    const float* Bptr1 = Bptr0 + (size_t)8 * DOUT;
    float acc[8][8] = {};
    for (int k0 = 0; k0 < DIN; k0 += 16) {
        float4 a0 = *(const float4*)(Aptr0 + k0);
        float4 a1 = *(const float4*)(Aptr1 + k0);
        float4 b0 = *(const float4*)(Bptr0 + (size_t)k0 * DOUT);
        float4 b1 = *(const float4*)(Bptr1 + (size_t)k0 * DOUT);
        __syncthreads();
        As[a_col + 0][a_row] = a0.x;
        As[a_col + 1][a_row] = a0.y;
        As[a_col + 2][a_row] = a0.z;
        As[a_col + 3][a_row] = a0.w;
        As[a_col + 0][a_row + 64] = a1.x;
        As[a_col + 1][a_row + 64] = a1.y;
        As[a_col + 2][a_row + 64] = a1.z;
        As[a_col + 3][a_row + 64] = a1.w;
        *(float4*)&Bs[b_row][b_col]     = b0;
        *(float4*)&Bs[b_row + 8][b_col] = b1;
        __syncthreads();
#pragma unroll
        for (int kk = 0; kk < 16; ++kk) {
            float ar[8], br[8];
#pragma unroll
            for (int i = 0; i < 8; ++i) ar[i] = As[kk][tr + i];
#pragma unroll
            for (int i = 0; i < 8; ++i) br[i] = Bs[kk][tc + i];
#pragma unroll
            for (int i = 0; i < 8; ++i)
#pragma unroll
                for (int jj = 0; jj < 8; ++jj)
                    acc[i][jj] = fmaf(ar[i], br[jj], acc[i][jj]);
        }
    }
    float bp[8];
#pragma unroll
    for (int jj = 0; jj < 8; ++jj)
        bp[jj] = bias[block_col + tc + jj] + probs[block_col + tc + jj];
#pragma unroll
    for (int i = 0; i < 8; ++i) {
        float* crow = C + (size_t)(block_row + tr + i) * DOUT + block_col + tc;
#pragma unroll
        for (int jj = 0; jj < 8; ++jj)
            crow[jj] = tanh_fast(acc[i][jj] + bp[jj]);
    }
}

extern "C" void kernel_launch(void* const* d_in, const int* in_sizes, int n_in,
                              void* d_out, int out_size, void* d_ws, size_t ws_size,
                              hipStream_t stream) {
    const float* x  = (const float*)d_in[0];  // [4096, 2048]
    const float* W  = (const float*)d_in[1];  // [16, 2048, 2048]
    const float* cw = (const float*)d_in[2];  // [2048, 2048]
    const float* cb = (const float*)d_in[3];  // [2048]
    float* out = (float*)d_out;

    // ws layout: probs f32[2048] | x_hi | x_lo | wt_hi | wt_lo  (bf16 bits as u16)
    const size_t PROBS_B = 8192;
    const size_t XSZ = (size_t)BATCH * DIN;   // 8388608
    const size_t WSZ = (size_t)DIN * DOUT;    // 4194304
    const size_t need = PROBS_B + 2 * XSZ * 2 + 2 * WSZ * 2;  // 50,339,840 B

    float* probs = (float*)d_ws;
    probs_kernel<<<DOUT / 16, 256, 0, stream>>>(W, probs);

    if (ws_size >= need) {
        u16* xh = (u16*)((char*)d_ws + PROBS_B);
        u16* xl = xh + XSZ;
        u16* wh = xl + XSZ;
        u16* wl = wh + WSZ;

        convert_x_kernel<<<XSZ / 4 / 256, 256, 0, stream>>>(x, xh, xl);
        transpose_w_kernel<<<dim3(DOUT / 32, DIN / 32), 256, 0, stream>>>(cw, wh, wl);

        dim3 grid(DOUT / 128, BATCH / 128);
        gemm_mfma_kernel<<<grid, 256, 0, stream>>>(xh, xl, wh, wl, cb, probs, out);
    } else {
        dim3 grid(DOUT / 128, BATCH / 128);
        gemm_tanh_kernel<<<grid, 256, 0, stream>>>(x, cw, cb, probs, out);
    }
}